// Round 3
// baseline (267.168 us; speedup 1.0000x reference)
//
#include <hip/hip_runtime.h>
#include <cstdint>
#include <cstddef>

// ---------- common ----------
typedef __bf16 bf16x8 __attribute__((ext_vector_type(8)));
typedef float  f32x4  __attribute__((ext_vector_type(4)));
typedef unsigned short u16x8 __attribute__((ext_vector_type(8)));

__device__ __forceinline__ uint16_t f2bf(float f) {
  uint32_t u = __float_as_uint(f);
  u += 0x7fffu + ((u >> 16) & 1u);          // round-to-nearest-even
  return (uint16_t)(u >> 16);
}
__device__ __forceinline__ float bf2f(uint16_t u) {
  return __uint_as_float((uint32_t)u << 16);
}
// packed f32x2 -> bf16x2 (dst.lo=lo, dst.hi=hi), RTNE in HW
__device__ __forceinline__ uint32_t cvtpk(float lo, float hi) {
  uint32_t r;
  asm("v_cvt_pk_bf16_f32 %0, %1, %2" : "=v"(r) : "v"(lo), "v"(hi));
  return r;
}

__device__ __forceinline__ f32x4 mfma16(bf16x8 a, bf16x8 b, f32x4 c) {
  return __builtin_amdgcn_mfma_f32_16x16x32_bf16(a, b, c, 0, 0, 0);
}

#define GLD_TO_LDS16(gptr, lptr)                                                   \
  __builtin_amdgcn_global_load_lds(                                                \
      (const __attribute__((address_space(1))) void*)(gptr),                       \
      (__attribute__((address_space(3))) void*)(lptr), 16, 0, 0)

// ---------- fused fp32 -> bf16 cast of all 4 tensors ----------
__global__ void cvt_all(const float* __restrict__ q, const float* __restrict__ k,
                        const float* __restrict__ w, const float* __restrict__ wo,
                        uint16_t* __restrict__ Xq, uint16_t* __restrict__ Xk,
                        uint16_t* __restrict__ Wb, uint16_t* __restrict__ Wob) {
  int i = blockIdx.x * blockDim.x + threadIdx.x;
  const float* src;
  uint16_t* dst;
  int off;
  if (i < 1048576)      { src = q;  dst = Xq;  off = i; }
  else if (i < 2097152) { src = k;  dst = Xk;  off = i - 1048576; }
  else if (i < 2883584) { src = w;  dst = Wb;  off = i - 2097152; }
  else                  { src = wo; dst = Wob; off = i - 2883584; }
  float4 v = ((const float4*)src)[off];
  ushort4 o;
  o.x = f2bf(v.x); o.y = f2bf(v.y); o.z = f2bf(v.z); o.w = f2bf(v.w);
  ((ushort4*)dst)[off] = o;
}

// ---------- pack hard (b,t,s) fp32 {0,1} -> bitmask ----------
__global__ void bitpack(const float* __restrict__ hard, uint32_t* __restrict__ bits) {
  int i = blockIdx.x * 256 + threadIdx.x;
  unsigned long long m = __ballot(hard[i] != 0.0f);
  if ((threadIdx.x & 63) == 0) {
    int w = i >> 5;
    bits[w]     = (uint32_t)m;
    bits[w + 1] = (uint32_t)(m >> 32);
  }
}

// ---------- fused Q + KV projection: 256x256 tile, BK=64, 8-wave ----------
// R10: R9's port serialized ds_read->lgkmcnt(0)->MFMA within each phase (the
// frag reads for phase p were issued right before p's MFMA). Fix: one-phase-
// ahead frag pipelining with double frag sets (a0/a1, b0/b1). Every lgkm wait
// before an MFMA is now a counted wait on reads issued a full phase earlier.
// Staging race: vmcnt(0)+barrier at end of ph2 precedes ph3's reads of the
// newly staged buffer; all reads of a buffer complete (lgkm wait before mm11)
// before any wave passes ph3's trailing barrier and re-stages it.
__global__ __launch_bounds__(512, 2)
void gemm_qkv8(const uint16_t* __restrict__ Xq, const uint16_t* __restrict__ Xk,
               const uint16_t* __restrict__ Wb, const float* __restrict__ ipb,
               uint16_t* __restrict__ Qb, uint16_t* __restrict__ Kb,
               uint16_t* __restrict__ Vt) {
  __shared__ __align__(16) char lds[131072];
  char* const Ab0 = lds;                 // 32 KB: A K-tile buf0 (256r x 128B)
  char* const Ab1 = lds + 32768;         // 32 KB: A buf1
  char* const Bb0 = lds + 65536;         // 32 KB: B buf0
  char* const Bb1 = lds + 98304;         // 32 KB: B buf1

  const int tid  = threadIdx.x;
  const int wave = tid >> 6, lane = tid & 63;
  const int quad = lane >> 4, l16 = lane & 15;
  const int wr = wave >> 2, wc = wave & 3;     // 2x4 wave grid
  const int sw = (l16 & 7) << 4;               // read-side XOR swizzle

  // block mapping, XCD-bijective swizzle (192 % 8 == 0)
  const int swz = (blockIdx.x & 7) * 24 + (blockIdx.x >> 3);
  const uint16_t *Ag, *Bg;
  const float* bias;
  int bm, bn, mode;
  if (swz < 64) { mode = 0; Ag = Xq; Bg = Wb;            bias = ipb;        bm = swz >> 2; bn = swz & 3; }
  else { int u = swz - 64;
         mode = 1; Ag = Xk; Bg = Wb + (1 << 20); bias = ipb + 1024; bm = u >> 3;  bn = u & 7; }

  const char* Agb = (const char*)Ag + (size_t)bm * 256 * 2048;
  const char* Bgb = (const char*)Bg + (size_t)bn * 256 * 2048;

  // staging: per-lane pre-swizzled source offset (row = ..+lane>>3, 16B slot
  // permuted by lane>>3 so the LINEAR lds write realizes the swizzled layout)
  const int lrow = lane >> 3;
  const size_t laneoff = (size_t)(wave * 8 + lrow) * 2048 + (((lane & 7) ^ lrow) << 4);

  // hr in [0,4): 64-row slab; dst is wave-uniform.
  auto stage = [&](const char* gb, char* lb, int hr, int tk) {
    GLD_TO_LDS16(gb + (size_t)hr * 131072 + (size_t)tk * 128 + laneoff,
                 lb + hr * 8192 + wave * 1024);
  };

  f32x4 acc[8][4] = {};
  bf16x8 a0[4][2], a1[4][2], b0[2][2], b1[2][2];

  auto rdA = [&](const char* Ac, int mh, bf16x8 (&a)[4][2]) {
#pragma unroll
    for (int mi = 0; mi < 4; mi++) {
      const char* p = Ac + (wr * 128 + mh * 64 + mi * 16 + l16) * 128;
#pragma unroll
      for (int ks = 0; ks < 2; ks++)
        a[mi][ks] = *(const bf16x8*)(p + ((ks * 64 + quad * 16) ^ sw));
    }
  };
  auto rdB = [&](const char* Bc, int nh, bf16x8 (&b)[2][2]) {
#pragma unroll
    for (int nj = 0; nj < 2; nj++) {
      const char* p = Bc + (wc * 64 + nh * 32 + nj * 16 + l16) * 128;
#pragma unroll
      for (int ks = 0; ks < 2; ks++)
        b[nj][ks] = *(const bf16x8*)(p + ((ks * 64 + quad * 16) ^ sw));
    }
  };
  auto mm = [&](int mh, int nh, bf16x8 (&a)[4][2], bf16x8 (&b)[2][2]) {
    __builtin_amdgcn_s_setprio(1);
#pragma unroll
    for (int ks = 0; ks < 2; ks++)
#pragma unroll
      for (int mi = 0; mi < 4; mi++)
#pragma unroll
        for (int nj = 0; nj < 2; nj++)
          acc[mh * 4 + mi][nh * 2 + nj] =
              mfma16(a[mi][ks], b[nj][ks], acc[mh * 4 + mi][nh * 2 + nj]);
    __builtin_amdgcn_s_setprio(0);
  };

  // one K-tile, frag reads pipelined one phase ahead
  auto ktile = [&](const char* Ac, const char* Bc, char* An, char* Bn,
                   int tn, bool pf) {
    // ph0: read b1 (for ph1's mm) || stage A slabs 0-2 of next tile
    rdB(Bc, 1, b1);
    if (pf) { stage(Agb, An, 0, tn); stage(Agb, An, 1, tn); stage(Agb, An, 2, tn); }
    __builtin_amdgcn_s_barrier();
    mm(0, 0, a0, b0);                       // frags read last phase
    __builtin_amdgcn_s_barrier();
    // ph1: read a1 (for ph2) || stage A3 + B slabs 0-3
    rdA(Ac, 1, a1);
    if (pf) { stage(Agb, An, 3, tn); stage(Bgb, Bn, 0, tn); stage(Bgb, Bn, 1, tn);
              stage(Bgb, Bn, 2, tn); stage(Bgb, Bn, 3, tn); }
    __builtin_amdgcn_s_barrier();
    mm(0, 1, a0, b1);
    __builtin_amdgcn_s_barrier();
    // ph2: no reads/stages; drain this tile's stages, all-waves sync
    mm(1, 0, a1, b0);
    asm volatile("s_waitcnt vmcnt(0)" ::: "memory");
    __builtin_amdgcn_s_barrier();
    // ph3: read next tile's first frags (nbuf now safe) || last quadrant
    if (pf) { rdA(An, 0, a0); rdB(Bn, 0, b0); }
    __builtin_amdgcn_s_barrier();
    mm(1, 1, a1, b1);
    __builtin_amdgcn_s_barrier();
  };

  // prologue: stage tile 0 into buf0, preload its first frags
#pragma unroll
  for (int hr = 0; hr < 4; hr++) stage(Agb, Ab0, hr, 0);
#pragma unroll
  for (int hr = 0; hr < 4; hr++) stage(Bgb, Bb0, hr, 0);
  asm volatile("s_waitcnt vmcnt(0)" ::: "memory");
  __builtin_amdgcn_s_barrier();
  rdA(Ab0, 0, a0); rdB(Bb0, 0, b0);

  for (int tt = 0; tt < 16; tt += 2) {
    ktile(Ab0, Bb0, Ab1, Bb1, tt + 1, true);          // compute t, stage t+1
    ktile(Ab1, Bb1, Ab0, Bb0, tt + 2, tt + 2 < 16);   // compute t+1, stage t+2
  }

  // epilogue: bias + mode-dependent scatter
#pragma unroll
  for (int mi = 0; mi < 8; mi++)
#pragma unroll
    for (int j = 0; j < 4; j++)
#pragma unroll
      for (int r = 0; r < 4; r++) {
        int grow = bm * 256 + wr * 128 + mi * 16 + quad * 4 + r;  // row = t*4+b
        int gf   = bn * 256 + wc * 64 + j * 16 + l16;
        float c = acc[mi][j][r] + bias[gf];
        if (mode == 0) {
          c *= 0.125f;  // HD^-0.5
          int tq = grow >> 2, bb = grow & 3, h = gf >> 6, d = gf & 63;
          Qb[((((size_t)bb * 16 + h) << 10) + tq) * 64 + d] = f2bf(c);
        } else {
          int s = grow >> 2, bb = grow & 3;
          if (gf < 1024) {
            int h = gf >> 6, d = gf & 63;
            Kb[((((size_t)bb * 16 + h) << 10) + s) * 64 + d] = f2bf(c);
          } else {
            int fv = gf - 1024, h = fv >> 6, d = fv & 63;
            Vt[((((size_t)bb * 16 + h) * 64 + d) << 10) + s] = f2bf(c);
          }
        }
      }
}

// ---------- out-projection, 64x128 tiles, grid 512 ----------
__global__ __launch_bounds__(256)
void gemm_out(const uint16_t* __restrict__ A, const uint16_t* __restrict__ B,
              const float* __restrict__ bias, float* __restrict__ o32) {
  __shared__ __align__(16) uint16_t As[64 * 32];
  __shared__ __align__(16) uint16_t Bs[128 * 32];
  const int tid  = threadIdx.x;
  const int wave = tid >> 6, lane = tid & 63;
  const int quad = lane >> 4, l16 = lane & 15;
  const int bm = blockIdx.x >> 3, bn = blockIdx.x & 7;
  const int wm = (wave >> 1) << 5, wn = (wave & 1) << 6;
  const int K = 1024;

  f32x4 acc[2][4] = {};

  for (int k0 = 0; k0 < K; k0 += 32) {
    __syncthreads();
    {
      int c   = wave * 64 + lane;
      int row = c >> 2, kc = c & 3;
      const uint16_t* ga = A + (size_t)(bm * 64 + row) * K + k0 + kc * 8;
      GLD_TO_LDS16(ga, As + (size_t)(wave * 64) * 8);
    }
#pragma unroll
    for (int j = 0; j < 2; j++) {
      int c   = wave * 128 + j * 64 + lane;
      int row = c >> 2, kc = c & 3;
      const uint16_t* gb = B + (size_t)(bn * 128 + row) * K + k0 + kc * 8;
      GLD_TO_LDS16(gb, Bs + (size_t)(wave * 128 + j * 64) * 8);
    }
    __syncthreads();

    bf16x8 af[2], bfr[4];
#pragma unroll
    for (int i = 0; i < 2; i++)
      af[i] = *(const bf16x8*)(As + (wm + i * 16 + l16) * 32 + quad * 8);
#pragma unroll
    for (int i = 0; i < 4; i++)
      bfr[i] = *(const bf16x8*)(Bs + (wn + i * 16 + l16) * 32 + quad * 8);
#pragma unroll
    for (int mi = 0; mi < 2; mi++)
#pragma unroll
      for (int ni = 0; ni < 4; ni++)
        acc[mi][ni] = mfma16(af[mi], bfr[ni], acc[mi][ni]);
  }

#pragma unroll
  for (int mi = 0; mi < 2; mi++)
#pragma unroll
    for (int ni = 0; ni < 4; ni++)
#pragma unroll
      for (int r = 0; r < 4; r++) {
        int gi = bm * 64 + wm + mi * 16 + quad * 4 + r;
        int gf = bn * 128 + wn + ni * 16 + l16;
        o32[(size_t)gi * 1024 + gf] = acc[mi][ni][r] + bias[gf];
      }
}

// ---------- attention v2: swapped-operand QK/PV, XOR-swizzled LDS ----------
__global__ __launch_bounds__(256, 2)
void attn_kernel(const uint16_t* __restrict__ qb, const uint16_t* __restrict__ kb,
                 const uint16_t* __restrict__ vtb, const uint32_t* __restrict__ bits,
                 uint16_t* __restrict__ attn_out, float* __restrict__ rlout) {
  __shared__ __align__(16) uint16_t Ks[128 * 64];    // [s][d] swizzled, 16 KB
  __shared__ __align__(16) uint16_t Vs[64 * 128];    // [d][s] swizzled, 16 KB
  __shared__ __align__(16) uint16_t Pb[4 * 32 * 128];// per-wave [t32][s128], 32 KB

  const int bid = blockIdx.x;              // 512 blocks
  const int xcd = bid & 7, j = bid >> 3;   // round-robin dispatch -> XCD
  const int slab = xcd * 8 + (j >> 3);     // 8 (b,h) slabs per XCD
  const int b = slab >> 4, h = slab & 15;
  const int t0 = (j & 7) << 7;             // 128 t-rows per block
  const int tid = threadIdx.x, wave = tid >> 6, lane = tid & 63;
  const int quad = lane >> 4, l16 = lane & 15;
  const int sw = (l16 & 7) << 4;           // XOR swizzle for row=l16 reads
  const size_t bh = (size_t)b * 16 + h;
  const int tw = t0 + wave * 32;
  const int ta = tw + l16, tb = ta + 16;   // lane's two t rows
  char* PwA = (char*)(Pb + wave * (32 * 128)) + l16 * 256;
  char* PwB = PwA + 16 * 256;

  // Q B-frags (op1: col=t=l16), rows ta / tb
  const uint16_t* qA = qb + ((bh << 10) + ta) * 64;
  bf16x8 aqA0 = *(const bf16x8*)(qA + quad * 8);
  bf16x8 aqA1 = *(const bf16x8*)(qA + 32 + quad * 8);
  bf16x8 aqB0 = *(const bf16x8*)(qA + 1024 + quad * 8);
  bf16x8 aqB1 = *(const bf16x8*)(qA + 1024 + 32 + quad * 8);

  f32x4 accA[4] = {}, accB[4] = {};
  float smA = 0.f, smB = 0.f;

  const int kr = tid >> 3, kc8 = tid & 7;    // K staging: 32 rows/round
  const int vr = tid >> 4, vc16 = tid & 15;  // V staging: 16 rows/round

  const uint32_t* bA = bits + (((size_t)(b << 10) + ta) << 5);
  const uint32_t* bB = bits + (((size_t)(b << 10) + tb) << 5);

  // prologue: coalesced loads of chunk 0 + its mask words
  u16x8 kreg[4], vreg[4];
#pragma unroll
  for (int r = 0; r < 4; r++)
    kreg[r] = *(const u16x8*)(kb + (bh << 16) + (size_t)(r * 256 + tid) * 8);
#pragma unroll
  for (int r = 0; r < 4; r++)
    vreg[r] = *(const u16x8*)(vtb + (((bh << 6) + r * 16 + vr) << 10) + vc16 * 8);
  uint4 uA = *(const uint4*)bA;
  uint4 uB = *(const uint4*)bB;

  for (int sc = 0; sc < 8; sc++) {
    // pre-shifted mask words for this chunk (from prefetched uA/uB)
    uint32_t wA[4] = {uA.x >> (quad * 4), uA.y >> (quad * 4),
                      uA.z >> (quad * 4), uA.w >> (quad * 4)};
    uint32_t wB[4] = {uB.x >> (quad * 4), uB.y >> (quad * 4),
                      uB.z >> (quad * 4), uB.w >> (quad * 4)};

    __syncthreads();  // prior chunk's LDS reads done; staging loads drained
#pragma unroll
    for (int r = 0; r < 4; r++) {
      const int row = r * 32 + kr;
      *(u16x8*)((char*)Ks + row * 128 + ((kc8 * 16) ^ ((row & 7) << 4))) = kreg[r];
    }
#pragma unroll
    for (int r = 0; r < 4; r++) {
      const int row = r * 16 + vr;
      *(u16x8*)((char*)Vs + row * 256 + ((vc16 * 16) ^ ((row & 7) << 4))) = vreg[r];
    }
    __syncthreads();  // staging visible

    if (sc < 7) {  // T14: issue next chunk's loads; latency hides under compute
      const uint16_t* kbase = kb + (bh << 16) + (size_t)(sc + 1) * 8192;
#pragma unroll
      for (int r = 0; r < 4; r++)
        kreg[r] = *(const u16x8*)(kbase + (size_t)(r * 256 + tid) * 8);
#pragma unroll
      for (int r = 0; r < 4; r++)
        vreg[r] = *(const u16x8*)(vtb + (((bh << 6) + r * 16 + vr) << 10) +
                                  (sc + 1) * 128 + vc16 * 8);
      uA = *(const uint4*)(bA + (sc + 1) * 4);
      uB = *(const uint4*)(bB + (sc + 1) * 4);
    }

    // QK^T (swapped: D[s=quad*4+r][t=l16]) + streamed exp -> packed P rows
#pragma unroll
    for (int nn = 0; nn < 8; nn++) {
      const char* kbp = (const char*)Ks + (nn * 16 + l16) * 128;
      bf16x8 bk0 = *(const bf16x8*)(kbp + ((quad * 16) ^ sw));
      bf16x8 bk1 = *(const bf16x8*)(kbp + ((64 + quad * 16) ^ sw));
      f32x4 cA = {}, cB = {};
      cA = mfma16(bk0, aqA0, cA); cA = mfma16(bk1, aqA1, cA);
      cB = mfma16(bk0, aqB0, cB); cB = mfma16(bk1, aqB1, cB);
      const uint32_t mA = wA[nn >> 1] >> ((nn & 1) * 16);
      const uint32_t mB = wB[nn >> 1] >> ((nn & 1) * 16);
      float eA[4], eB[4];
#pragma unroll
      for (int r = 0; r < 4; r++) {
        eA[r] = __expf(cA[r]); smA += eA[r];
        eB[r] = __expf(cB[r]); smB += eB[r];
        eA[r] = ((mA >> r) & 1) ? eA[r] : 0.f;  // mask AFTER rowsum (softmax*hard)
        eB[r] = ((mB >> r) & 1) ? eB[r] : 0.f;
      }
      const int pc = (nn * 32 + quad * 8) ^ sw;
      *(uint2*)(PwA + pc) = make_uint2(cvtpk(eA[0], eA[1]), cvtpk(eA[2], eA[3]));
      *(uint2*)(PwB + pc) = make_uint2(cvtpk(eB[0], eB[1]), cvtpk(eB[2], eB[3]));
    }

    // PV (swapped: D[d=quad*4+r][t=l16]); P wave-private -> no barrier
#pragma unroll
    for (int kc = 0; kc < 4; kc++) {
      const int pcb = (kc * 64 + quad * 16) ^ sw;
      bf16x8 apA = *(const bf16x8*)(PwA + pcb);
      bf16x8 apB = *(const bf16x8*)(PwB + pcb);
#pragma unroll
      for (int dt = 0; dt < 4; dt++) {
        bf16x8 bv = *(const bf16x8*)((const char*)Vs + (dt * 16 + l16) * 256 +
                                     ((kc * 64 + quad * 16) ^ sw));
        accA[dt] = mfma16(bv, apA, accA[dt]);
        accB[dt] = mfma16(bv, apB, accB[dt]);
      }
    }
  }

  // row-sums: t is lane-local; reduce across quads only
  smA += __shfl_xor(smA, 16); smA += __shfl_xor(smA, 32);
  smB += __shfl_xor(smB, 16); smB += __shfl_xor(smB, 32);
  const float rlA = 1.0f / smA, rlB = 1.0f / smB;
  if (quad == 0) rlout[(bh << 10) + ta] = rlA;
  if (quad == 1) rlout[(bh << 10) + tb] = rlB;

  // O epilogue: 4 consecutive d per lane -> packed 8B stores
#pragma unroll
  for (int dt = 0; dt < 4; dt++) {
    uint2 oA = make_uint2(cvtpk(accA[dt][0] * rlA, accA[dt][1] * rlA),
                          cvtpk(accA[dt][2] * rlA, accA[dt][3] * rlA));
    *(uint2*)(attn_out + ((size_t)(ta * 4 + b) << 10) + h * 64 + dt * 16 + quad * 4) = oA;
    uint2 oB = make_uint2(cvtpk(accB[dt][0] * rlB, accB[dt][1] * rlB),
                          cvtpk(accB[dt][2] * rlB, accB[dt][3] * rlB));
    *(uint2*)(attn_out + ((size_t)(tb * 4 + b) << 10) + h * 64 + dt * 16 + quad * 4) = oB;
  }
}

// ---------- avg v2: swapped-operand QK, swizzled K, float4 stores ----------
__global__ __launch_bounds__(256, 2)
void avg_kernel(const uint16_t* __restrict__ qb, const uint16_t* __restrict__ kb,
                const float* __restrict__ rlin, const uint32_t* __restrict__ bits,
                float* __restrict__ avgout) {
  __shared__ __align__(16) uint16_t Ks[128 * 64];  // swizzled, 16 KB

  const int bid = blockIdx.x;
  const int xcd = bid & 7, j = bid >> 3;   // 512 blocks: xcd 0..7, j 0..63
  const int b  = xcd >> 1;
  const int t0 = ((xcd & 1) * 8 + (j >> 3)) << 6;
  const int s0 = (j & 7) << 7;
  const int tid = threadIdx.x, wave = tid >> 6, lane = tid & 63;
  const int quad = lane >> 4, l16 = lane & 15;
  const int sw = (l16 & 7) << 4;
  const int tr = t0 + wave * 16 + l16;     // lane's t row
  const int kr = tid >> 3, kc8 = tid & 7;

  // mask words for row tr, cols [s0, s0+128), pre-shifted by quad*4
  uint4 u = *(const uint4*)(bits + (((size_t)(b << 10) + tr) << 5) + (s0 >> 5));
  uint32_t w4[4] = {u.x >> (quad * 4), u.y >> (quad * 4),
                    u.z >> (quad * 4), u.w >> (quad * 4)};

  float av[8][4] = {};

  u16x8 kreg[4];
  {
    const uint16_t* kb0 = kb + ((((size_t)b * 16) << 10) + s0) * 64;
#pragma unroll
    for (int r = 0; r < 4; r++)
      kreg[r] = *(const u16x8*)(kb0 + (size_t)(r * 256 + tid) * 8);
  }

  for (int hh = 0; hh < 16; hh++) {
    __syncthreads();
#pragma unroll
    for (int r = 0; r < 4; r++) {
      const int row = r * 32 + kr;
      *(u16x8*)((char*)Ks + row * 128 + ((kc8 * 16) ^ ((row & 7) << 4))) = kreg[r];
    }
    __syncthreads();
    if (hh < 15) {  // prefetch next head's K-tile under compute
      const uint16_t* kb2 = kb + ((((size_t)b * 16 + hh + 1) << 10) + s0) * 64;
#pragma unroll
      for (int r = 0; r < 4; r++)
        kreg[r] = *(const u16x8*)(kb2 + (size_t)(r * 256 + tid) * 8);
    }

    const size_t bh = (size_t)b * 16 + hh;
    const uint16_t* qrow = qb + ((bh << 10) + tr) * 64;
    bf16x8 aq0 = *(const bf16x8*)(qrow + quad * 8);
    bf16x8 aq1 = *(const bf16x8*)(qrow + 32 + quad * 8);
    const float rl = rlin[(bh << 10) + tr];

#pragma unroll
    for (int n = 0; n < 8; n++) {
      const char* kbp = (const char*)Ks + (n * 16 + l16) * 128;
      bf16x8 bk0 = *(const bf16x8*)(kbp + ((quad * 16) ^ sw));
      bf16x8 bk1 = *(const bf16x8*)(kbp + ((64 + quad * 16) ^ sw));
      f32x4 c = {};
      c = mfma16(bk0, aq0, c);
      c = mfma16(bk1, aq1, c);
#pragma unroll
      for (int r = 0; r < 4; r++) av[n][r] += __expf(c[r]) * rl;
    }
  }

  float* orow = avgout + ((size_t)(b << 10) + tr) * 1024 + s0 + quad * 4;
#pragma unroll
  for (int n = 0; n < 8; n++) {
    const uint32_t m = w4[n >> 1] >> ((n & 1) * 16);
    float4 f;
    f.x = av[n][0] * (((m >> 0) & 1) ? 0.0625f : 0.f);
    f.y = av[n][1] * (((m >> 1) & 1) ? 0.0625f : 0.f);
    f.z = av[n][2] * (((m >> 2) & 1) ? 0.0625f : 0.f);
    f.w = av[n][3] * (((m >> 3) & 1) ? 0.0625f : 0.f);
    *(float4*)(orow + n * 16) = f;
  }
}

// ---------- launch ----------
extern "C" void kernel_launch(void* const* d_in, const int* in_sizes, int n_in,
                              void* d_out, int out_size, void* d_ws, size_t ws_size,
                              hipStream_t stream) {
  const float* query = (const float*)d_in[0];
  const float* key   = (const float*)d_in[1];
  const float* hard  = (const float*)d_in[2];
  const float* ipw   = (const float*)d_in[3];
  const float* ipb   = (const float*)d_in[4];
  const float* opw   = (const float*)d_in[5];
  const float* opb   = (const float*)d_in[6];

  char* ws = (char*)d_ws;
  const size_t MB = 1ull << 20;
  uint16_t* Xq  = (uint16_t*)(ws + 0);        // 8 MB (reused as attn_out)
  uint16_t* Xk  = (uint16_t*)(ws + 8 * MB);   // 8 MB
  uint16_t* Wb  = (uint16_t*)(ws + 16 * MB);  // 6 MB
  uint16_t* Wob = (uint16_t*)(ws + 22 * MB);  // 2 MB
  uint16_t* Qb  = (uint16_t*)(ws + 24 * MB);  // 8 MB (b,h,t,d)
  uint16_t* Kb  = (uint16_t*)(ws + 32 * MB);  // 8 MB (b,h,s,d)
  uint16_t* Vt  = (uint16_t*)(ws + 40 * MB);  // 8 MB (b,h,d,s)
  uint16_t* AO  = Xq;                         // alias: Xq dead after gemm_qkv8

  float* out = (float*)d_out;
  float* avg = out + 4194304;
  // bits (512 KB) + rlout (256 KB) parked in the out region: dead until
  // gemm_out, which runs last and overwrites them with the real output.
  uint32_t* bits  = (uint32_t*)out;
  float*    rlbuf = out + 131072;

  cvt_all<<<12288, 256, 0, stream>>>(query, key, ipw, opw, Xq, Xk, Wb, Wob);
  bitpack<<<16384, 256, 0, stream>>>(hard, bits);

  // fused Q-proj (64 blocks) + KV-proj (128 blocks), pipelined 8-phase 256^2
  gemm_qkv8<<<192, 512, 0, stream>>>(Xq, Xk, Wb, ipb, Qb, Kb, Vt);

  // attention (swapped-operand, swizzled LDS, 128 t-rows/block): AO + 1/rowsum
  attn_kernel<<<512, 256, 0, stream>>>(Qb, Kb, Vt, bits, AO, rlbuf);

  // head-averaged attention map (swapped-operand, K staged+prefetched)
  avg_kernel<<<512, 256, 0, stream>>>(Qb, Kb, rlbuf, bits, avg);

  // out = AO @ Wo^T + bias (fp32 direct to d_out; overwrites bits/rlbuf)
  gemm_out<<<512, 256, 0, stream>>>(AO, Wob, opb, out);
}

// Round 5
// 229.678 us; speedup vs baseline: 1.1632x; 1.1632x over previous
//
#include <hip/hip_runtime.h>
#include <cstdint>
#include <cstddef>

// ---------- common ----------
typedef __bf16 bf16x8 __attribute__((ext_vector_type(8)));
typedef float  f32x4  __attribute__((ext_vector_type(4)));
typedef unsigned short u16x8 __attribute__((ext_vector_type(8)));

__device__ __forceinline__ uint16_t f2bf(float f) {
  uint32_t u = __float_as_uint(f);
  u += 0x7fffu + ((u >> 16) & 1u);          // round-to-nearest-even
  return (uint16_t)(u >> 16);
}
__device__ __forceinline__ float bf2f(uint16_t u) {
  return __uint_as_float((uint32_t)u << 16);
}
// packed f32x2 -> bf16x2 (dst.lo=lo, dst.hi=hi), RTNE in HW
__device__ __forceinline__ uint32_t cvtpk(float lo, float hi) {
  uint32_t r;
  asm("v_cvt_pk_bf16_f32 %0, %1, %2" : "=v"(r) : "v"(lo), "v"(hi));
  return r;
}

__device__ __forceinline__ f32x4 mfma16(bf16x8 a, bf16x8 b, f32x4 c) {
  return __builtin_amdgcn_mfma_f32_16x16x32_bf16(a, b, c, 0, 0, 0);
}

#define GLD_TO_LDS16(gptr, lptr)                                                   \
  __builtin_amdgcn_global_load_lds(                                                \
      (const __attribute__((address_space(1))) void*)(gptr),                       \
      (__attribute__((address_space(3))) void*)(lptr), 16, 0, 0)

// ---------- prep: fused fp32->bf16 cast of 4 tensors + hard bitpack ----------
__global__ void prep(const float* __restrict__ q, const float* __restrict__ k,
                     const float* __restrict__ w, const float* __restrict__ wo,
                     const float* __restrict__ hard,
                     uint16_t* __restrict__ Xq, uint16_t* __restrict__ Xk,
                     uint16_t* __restrict__ Wb, uint16_t* __restrict__ Wob,
                     uint32_t* __restrict__ bits) {
  const int bid = blockIdx.x;
  if (bid < 12288) {
    int i = bid * 256 + threadIdx.x;
    const float* src;
    uint16_t* dst;
    int off;
    if (i < 1048576)      { src = q;  dst = Xq;  off = i; }
    else if (i < 2097152) { src = k;  dst = Xk;  off = i - 1048576; }
    else if (i < 2883584) { src = w;  dst = Wb;  off = i - 2097152; }
    else                  { src = wo; dst = Wob; off = i - 2883584; }
    float4 v = ((const float4*)src)[off];
    ushort4 o;
    o.x = f2bf(v.x); o.y = f2bf(v.y); o.z = f2bf(v.z); o.w = f2bf(v.w);
    ((ushort4*)dst)[off] = o;
  } else {
    int i = (bid - 12288) * 256 + threadIdx.x;
    unsigned long long m = __ballot(hard[i] != 0.0f);
    if ((threadIdx.x & 63) == 0) {
      int wd = i >> 5;
      bits[wd]     = (uint32_t)m;
      bits[wd + 1] = (uint32_t)(m >> 32);
    }
  }
}

// ---------- fused Q + KV projection, 128x128 tiles, grid 768 ----------
// R11: reverted to the R1 2-phase structure (measured 52.2-52.9 us; both
// 8-phase ports regressed). Added T1 bijective XCD swizzle (768 = 8*96):
// same-bm blocks land on one XCD -> A-panel fetched once per XCD instead
// of 8x (R1 FETCH 68.7 MB, ~35 ideal).
__global__ __launch_bounds__(256)
void gemm_qkv(const uint16_t* __restrict__ Xq, const uint16_t* __restrict__ Xk,
              const uint16_t* __restrict__ Wb, const float* __restrict__ ipb,
              uint16_t* __restrict__ Qb, uint16_t* __restrict__ Kb,
              uint16_t* __restrict__ Vt) {
  __shared__ __align__(16) uint16_t As[128 * 32];
  __shared__ __align__(16) uint16_t Bs[128 * 32];
  const int tid  = threadIdx.x;
  const int wave = tid >> 6, lane = tid & 63;
  const int quad = lane >> 4, l16 = lane & 15;

  const int swz = (blockIdx.x & 7) * 96 + (blockIdx.x >> 3);  // XCD-bijective
  const uint16_t *A, *B;
  const float* bias;
  int bm, bn, mode;
  if (swz < 256) {
    mode = 0; A = Xq; B = Wb; bias = ipb;
    bm = swz >> 3; bn = swz & 7;
  } else {
    mode = 1; A = Xk; B = Wb + (1 << 20); bias = ipb + 1024;
    int t = swz - 256; bm = t >> 4; bn = t & 15;
  }
  const int wm = (wave >> 1) << 6, wn = (wave & 1) << 6;
  const int K = 1024;

  f32x4 acc[4][4] = {};

  for (int k0 = 0; k0 < K; k0 += 32) {
    __syncthreads();
#pragma unroll
    for (int j = 0; j < 2; j++) {
      int c   = wave * 128 + j * 64 + lane;
      int row = c >> 2, kc = c & 3;
      const uint16_t* ga = A + (size_t)(bm * 128 + row) * K + k0 + kc * 8;
      GLD_TO_LDS16(ga, As + (size_t)(wave * 128 + j * 64) * 8);
      const uint16_t* gb = B + (size_t)(bn * 128 + row) * K + k0 + kc * 8;
      GLD_TO_LDS16(gb, Bs + (size_t)(wave * 128 + j * 64) * 8);
    }
    __syncthreads();

    bf16x8 af[4], bfr[4];
#pragma unroll
    for (int i = 0; i < 4; i++) {
      af[i]  = *(const bf16x8*)(As + (wm + i * 16 + l16) * 32 + quad * 8);
      bfr[i] = *(const bf16x8*)(Bs + (wn + i * 16 + l16) * 32 + quad * 8);
    }
#pragma unroll
    for (int mi = 0; mi < 4; mi++)
#pragma unroll
      for (int ni = 0; ni < 4; ni++)
        acc[mi][ni] = mfma16(af[mi], bfr[ni], acc[mi][ni]);
  }

#pragma unroll
  for (int mi = 0; mi < 4; mi++)
#pragma unroll
    for (int ni = 0; ni < 4; ni++)
#pragma unroll
      for (int r = 0; r < 4; r++) {
        int gi = bm * 128 + wm + mi * 16 + quad * 4 + r;  // row = t*4+b
        int gf = bn * 128 + wn + ni * 16 + l16;
        float c = acc[mi][ni][r] + bias[gf];
        if (mode == 0) {
          c *= 0.125f;  // HD^-0.5
          int t = gi >> 2, b = gi & 3, h = gf >> 6, d = gf & 63;
          Qb[((((size_t)b * 16 + h) * 1024 + t) << 6) + d] = f2bf(c);
        } else {
          int s = gi >> 2, b = gi & 3;
          if (gf < 1024) {
            int h = gf >> 6, d = gf & 63;
            Kb[((((size_t)b * 16 + h) * 1024 + s) << 6) + d] = f2bf(c);
          } else {
            int fv = gf - 1024, h = fv >> 6, d = fv & 63;
            Vt[((((size_t)b * 16 + h) * 64 + d) << 10) + s] = f2bf(c);
          }
        }
      }
}

// ---------- attention: swapped-operand QK/PV, XOR-swizzled LDS ----------
__global__ __launch_bounds__(256, 2)
void attn_kernel(const uint16_t* __restrict__ qb, const uint16_t* __restrict__ kb,
                 const uint16_t* __restrict__ vtb, const uint32_t* __restrict__ bits,
                 uint16_t* __restrict__ attn_out, float* __restrict__ rlout) {
  __shared__ __align__(16) uint16_t Ks[128 * 64];    // [s][d] swizzled, 16 KB
  __shared__ __align__(16) uint16_t Vs[64 * 128];    // [d][s] swizzled, 16 KB
  __shared__ __align__(16) uint16_t Pb[4 * 32 * 128];// per-wave [t32][s128], 32 KB

  const int bid = blockIdx.x;              // 512 blocks
  const int xcd = bid & 7, j = bid >> 3;   // round-robin dispatch -> XCD
  const int slab = xcd * 8 + (j >> 3);     // 8 (b,h) slabs per XCD
  const int b = slab >> 4, h = slab & 15;
  const int t0 = (j & 7) << 7;             // 128 t-rows per block
  const int tid = threadIdx.x, wave = tid >> 6, lane = tid & 63;
  const int quad = lane >> 4, l16 = lane & 15;
  const int sw = (l16 & 7) << 4;           // XOR swizzle for row=l16 reads
  const size_t bh = (size_t)b * 16 + h;
  const int tw = t0 + wave * 32;
  const int ta = tw + l16, tb = ta + 16;   // lane's two t rows
  char* PwA = (char*)(Pb + wave * (32 * 128)) + l16 * 256;
  char* PwB = PwA + 16 * 256;

  // Q B-frags (op1: col=t=l16), rows ta / tb
  const uint16_t* qA = qb + ((bh << 10) + ta) * 64;
  bf16x8 aqA0 = *(const bf16x8*)(qA + quad * 8);
  bf16x8 aqA1 = *(const bf16x8*)(qA + 32 + quad * 8);
  bf16x8 aqB0 = *(const bf16x8*)(qA + 1024 + quad * 8);
  bf16x8 aqB1 = *(const bf16x8*)(qA + 1024 + 32 + quad * 8);

  f32x4 accA[4] = {}, accB[4] = {};
  float smA = 0.f, smB = 0.f;

  const int kr = tid >> 3, kc8 = tid & 7;    // K staging: 32 rows/round
  const int vr = tid >> 4, vc16 = tid & 15;  // V staging: 16 rows/round

  const uint32_t* bA = bits + (((size_t)(b << 10) + ta) << 5);
  const uint32_t* bB = bits + (((size_t)(b << 10) + tb) << 5);

  // prologue: coalesced loads of chunk 0 + its mask words
  u16x8 kreg[4], vreg[4];
#pragma unroll
  for (int r = 0; r < 4; r++)
    kreg[r] = *(const u16x8*)(kb + (bh << 16) + (size_t)(r * 256 + tid) * 8);
#pragma unroll
  for (int r = 0; r < 4; r++)
    vreg[r] = *(const u16x8*)(vtb + (((bh << 6) + r * 16 + vr) << 10) + vc16 * 8);
  uint4 uA = *(const uint4*)bA;
  uint4 uB = *(const uint4*)bB;

  for (int sc = 0; sc < 8; sc++) {
    // pre-shifted mask words for this chunk (from prefetched uA/uB)
    uint32_t wA[4] = {uA.x >> (quad * 4), uA.y >> (quad * 4),
                      uA.z >> (quad * 4), uA.w >> (quad * 4)};
    uint32_t wB[4] = {uB.x >> (quad * 4), uB.y >> (quad * 4),
                      uB.z >> (quad * 4), uB.w >> (quad * 4)};

    __syncthreads();  // prior chunk's LDS reads done; staging loads drained
#pragma unroll
    for (int r = 0; r < 4; r++) {
      const int row = r * 32 + kr;
      *(u16x8*)((char*)Ks + row * 128 + ((kc8 * 16) ^ ((row & 7) << 4))) = kreg[r];
    }
#pragma unroll
    for (int r = 0; r < 4; r++) {
      const int row = r * 16 + vr;
      *(u16x8*)((char*)Vs + row * 256 + ((vc16 * 16) ^ ((row & 7) << 4))) = vreg[r];
    }
    __syncthreads();  // staging visible

    if (sc < 7) {  // T14: issue next chunk's loads; latency hides under compute
      const uint16_t* kbase = kb + (bh << 16) + (size_t)(sc + 1) * 8192;
#pragma unroll
      for (int r = 0; r < 4; r++)
        kreg[r] = *(const u16x8*)(kbase + (size_t)(r * 256 + tid) * 8);
#pragma unroll
      for (int r = 0; r < 4; r++)
        vreg[r] = *(const u16x8*)(vtb + (((bh << 6) + r * 16 + vr) << 10) +
                                  (sc + 1) * 128 + vc16 * 8);
      uA = *(const uint4*)(bA + (sc + 1) * 4);
      uB = *(const uint4*)(bB + (sc + 1) * 4);
    }

    // QK^T (swapped: D[s=quad*4+r][t=l16]) + streamed exp -> packed P rows
#pragma unroll
    for (int nn = 0; nn < 8; nn++) {
      const char* kbp = (const char*)Ks + (nn * 16 + l16) * 128;
      bf16x8 bk0 = *(const bf16x8*)(kbp + ((quad * 16) ^ sw));
      bf16x8 bk1 = *(const bf16x8*)(kbp + ((64 + quad * 16) ^ sw));
      f32x4 cA = {}, cB = {};
      cA = mfma16(bk0, aqA0, cA); cA = mfma16(bk1, aqA1, cA);
      cB = mfma16(bk0, aqB0, cB); cB = mfma16(bk1, aqB1, cB);
      const uint32_t mA = wA[nn >> 1] >> ((nn & 1) * 16);
      const uint32_t mB = wB[nn >> 1] >> ((nn & 1) * 16);
      float eA[4], eB[4];
#pragma unroll
      for (int r = 0; r < 4; r++) {
        eA[r] = __expf(cA[r]); smA += eA[r];
        eB[r] = __expf(cB[r]); smB += eB[r];
        eA[r] = ((mA >> r) & 1) ? eA[r] : 0.f;  // mask AFTER rowsum (softmax*hard)
        eB[r] = ((mB >> r) & 1) ? eB[r] : 0.f;
      }
      const int pc = (nn * 32 + quad * 8) ^ sw;
      *(uint2*)(PwA + pc) = make_uint2(cvtpk(eA[0], eA[1]), cvtpk(eA[2], eA[3]));
      *(uint2*)(PwB + pc) = make_uint2(cvtpk(eB[0], eB[1]), cvtpk(eB[2], eB[3]));
    }

    // PV (swapped: D[d=quad*4+r][t=l16]); P wave-private -> no barrier
#pragma unroll
    for (int kc = 0; kc < 4; kc++) {
      const int pcb = (kc * 64 + quad * 16) ^ sw;
      bf16x8 apA = *(const bf16x8*)(PwA + pcb);
      bf16x8 apB = *(const bf16x8*)(PwB + pcb);
#pragma unroll
      for (int dt = 0; dt < 4; dt++) {
        bf16x8 bv = *(const bf16x8*)((const char*)Vs + (dt * 16 + l16) * 256 +
                                     ((kc * 64 + quad * 16) ^ sw));
        accA[dt] = mfma16(bv, apA, accA[dt]);
        accB[dt] = mfma16(bv, apB, accB[dt]);
      }
    }
  }

  // row-sums: t is lane-local; reduce across quads only
  smA += __shfl_xor(smA, 16); smA += __shfl_xor(smA, 32);
  smB += __shfl_xor(smB, 16); smB += __shfl_xor(smB, 32);
  const float rlA = 1.0f / smA, rlB = 1.0f / smB;
  if (quad == 0) rlout[(bh << 10) + ta] = rlA;
  if (quad == 1) rlout[(bh << 10) + tb] = rlB;

  // O epilogue: 4 consecutive d per lane -> packed 8B stores
#pragma unroll
  for (int dt = 0; dt < 4; dt++) {
    uint2 oA = make_uint2(cvtpk(accA[dt][0] * rlA, accA[dt][1] * rlA),
                          cvtpk(accA[dt][2] * rlA, accA[dt][3] * rlA));
    *(uint2*)(attn_out + ((size_t)(ta * 4 + b) << 10) + h * 64 + dt * 16 + quad * 4) = oA;
    uint2 oB = make_uint2(cvtpk(accB[dt][0] * rlB, accB[dt][1] * rlB),
                          cvtpk(accB[dt][2] * rlB, accB[dt][3] * rlB));
    *(uint2*)(attn_out + ((size_t)(tb * 4 + b) << 10) + h * 64 + dt * 16 + quad * 4) = oB;
  }
}

// ---------- tail: fused avg (blocks 0..511) + out-projection (512..1023) ----
// avg and gemm_out are data-independent (avg: Qb/Kb/rl/hard; out: AO/Wob) but
// were serialized on the stream, each leaving the GPU half-idle at its tail.
// Fused at 4 blocks/CU they co-schedule (avg = VALU/exp-heavy, out =
// MFMA/VMEM-heavy). Race-free by construction: rl lives in ws (Xk region,
// dead after gemm_qkv); avg reads the mask from the immutable `hard` input
// (bits is only read by attn, which completes before this launch); out's
// stores only touch d_out[0..16MB) which nothing here reads.
__global__ __launch_bounds__(256, 4)
void tail(const uint16_t* __restrict__ qb, const uint16_t* __restrict__ kb,
          const float* __restrict__ rlin, const float* __restrict__ hard,
          const uint16_t* __restrict__ Ao, const uint16_t* __restrict__ Bw,
          const float* __restrict__ opb,
          float* __restrict__ out, float* __restrict__ avgout) {
  __shared__ __align__(16) char smem[16384];
  const int bid = blockIdx.x;
  const int tid = threadIdx.x, wave = tid >> 6, lane = tid & 63;
  const int quad = lane >> 4, l16 = lane & 15;

  if (bid < 512) {
    // ---- avg path: swapped-operand QK, swizzled K, float4 stores ----
    uint16_t* Ks = (uint16_t*)smem;          // 16 KB swizzled K-tile
    const int xcd = bid & 7, j = bid >> 3;
    const int b  = xcd >> 1;
    const int t0 = ((xcd & 1) * 8 + (j >> 3)) << 6;
    const int s0 = (j & 7) << 7;
    const int sw = (l16 & 7) << 4;
    const int tr = t0 + wave * 16 + l16;     // lane's t row
    const int kr = tid >> 3, kc8 = tid & 7;

    float av[8][4] = {};

    u16x8 kreg[4];
    {
      const uint16_t* kb0 = kb + ((((size_t)b * 16) << 10) + s0) * 64;
#pragma unroll
      for (int r = 0; r < 4; r++)
        kreg[r] = *(const u16x8*)(kb0 + (size_t)(r * 256 + tid) * 8);
    }

    for (int hh = 0; hh < 16; hh++) {
      __syncthreads();
#pragma unroll
      for (int r = 0; r < 4; r++) {
        const int row = r * 32 + kr;
        *(u16x8*)((char*)Ks + row * 128 + ((kc8 * 16) ^ ((row & 7) << 4))) = kreg[r];
      }
      __syncthreads();
      if (hh < 15) {  // prefetch next head's K-tile under compute
        const uint16_t* kb2 = kb + ((((size_t)b * 16 + hh + 1) << 10) + s0) * 64;
#pragma unroll
        for (int r = 0; r < 4; r++)
          kreg[r] = *(const u16x8*)(kb2 + (size_t)(r * 256 + tid) * 8);
      }

      const size_t bh = (size_t)b * 16 + hh;
      const uint16_t* qrow = qb + ((bh << 10) + tr) * 64;
      bf16x8 aq0 = *(const bf16x8*)(qrow + quad * 8);
      bf16x8 aq1 = *(const bf16x8*)(qrow + 32 + quad * 8);
      const float rl = rlin[(bh << 10) + tr];

#pragma unroll
      for (int n = 0; n < 8; n++) {
        const char* kbp = (const char*)Ks + (n * 16 + l16) * 128;
        bf16x8 bk0 = *(const bf16x8*)(kbp + ((quad * 16) ^ sw));
        bf16x8 bk1 = *(const bf16x8*)(kbp + ((64 + quad * 16) ^ sw));
        f32x4 c = {};
        c = mfma16(bk0, aq0, c);
        c = mfma16(bk1, aq1, c);
#pragma unroll
        for (int r = 0; r < 4; r++) av[n][r] += __expf(c[r]) * rl;
      }
    }

    // mask directly from immutable hard input (fp32 {0,1}), float4 per n
    const float* hrow = hard + (((size_t)(b << 10) + tr) << 10) + s0 + quad * 4;
    float* orow = avgout + ((size_t)(b << 10) + tr) * 1024 + s0 + quad * 4;
#pragma unroll
    for (int n = 0; n < 8; n++) {
      float4 hm = *(const float4*)(hrow + n * 16);
      float4 f;
      f.x = av[n][0] * (hm.x != 0.f ? 0.0625f : 0.f);
      f.y = av[n][1] * (hm.y != 0.f ? 0.0625f : 0.f);
      f.z = av[n][2] * (hm.z != 0.f ? 0.0625f : 0.f);
      f.w = av[n][3] * (hm.w != 0.f ? 0.0625f : 0.f);
      *(float4*)(orow + n * 16) = f;
    }
  } else {
    // ---- out-projection path: 64x128 tiles, XCD swizzle (512 = 8*64) ----
    uint16_t* As = (uint16_t*)smem;            // 4 KB
    uint16_t* Bs = (uint16_t*)(smem + 4096);   // 8 KB
    const int u = bid - 512;
    const int swz = (u & 7) * 64 + (u >> 3);   // same-bm blocks on one XCD
    const int bm = swz >> 3, bn = swz & 7;
    const int wm = (wave >> 1) << 5, wn = (wave & 1) << 6;
    const int K = 1024;

    f32x4 acc[2][4] = {};

    for (int k0 = 0; k0 < K; k0 += 32) {
      __syncthreads();
      {
        int c   = wave * 64 + lane;
        int row = c >> 2, kc = c & 3;
        const uint16_t* ga = Ao + (size_t)(bm * 64 + row) * K + k0 + kc * 8;
        GLD_TO_LDS16(ga, As + (size_t)(wave * 64) * 8);
      }
#pragma unroll
      for (int jj = 0; jj < 2; jj++) {
        int c   = wave * 128 + jj * 64 + lane;
        int row = c >> 2, kc = c & 3;
        const uint16_t* gb = Bw + (size_t)(bn * 128 + row) * K + k0 + kc * 8;
        GLD_TO_LDS16(gb, Bs + (size_t)(wave * 128 + jj * 64) * 8);
      }
      __syncthreads();

      bf16x8 af[2], bfr[4];
#pragma unroll
      for (int i = 0; i < 2; i++)
        af[i] = *(const bf16x8*)(As + (wm + i * 16 + l16) * 32 + quad * 8);
#pragma unroll
      for (int i = 0; i < 4; i++)
        bfr[i] = *(const bf16x8*)(Bs + (wn + i * 16 + l16) * 32 + quad * 8);
#pragma unroll
      for (int mi = 0; mi < 2; mi++)
#pragma unroll
        for (int ni = 0; ni < 4; ni++)
          acc[mi][ni] = mfma16(af[mi], bfr[ni], acc[mi][ni]);
    }

#pragma unroll
    for (int mi = 0; mi < 2; mi++)
#pragma unroll
      for (int ni = 0; ni < 4; ni++)
#pragma unroll
        for (int r = 0; r < 4; r++) {
          int gi = bm * 64 + wm + mi * 16 + quad * 4 + r;
          int gf = bn * 128 + wn + ni * 16 + l16;
          out[(size_t)gi * 1024 + gf] = acc[mi][ni][r] + opb[gf];
        }
  }
}

// ---------- launch ----------
extern "C" void kernel_launch(void* const* d_in, const int* in_sizes, int n_in,
                              void* d_out, int out_size, void* d_ws, size_t ws_size,
                              hipStream_t stream) {
  const float* query = (const float*)d_in[0];
  const float* key   = (const float*)d_in[1];
  const float* hard  = (const float*)d_in[2];
  const float* ipw   = (const float*)d_in[3];
  const float* ipb   = (const float*)d_in[4];
  const float* opw   = (const float*)d_in[5];
  const float* opb   = (const float*)d_in[6];

  char* ws = (char*)d_ws;
  const size_t MB = 1ull << 20;
  uint16_t* Xq  = (uint16_t*)(ws + 0);        // 8 MB (reused as attn_out)
  uint16_t* Xk  = (uint16_t*)(ws + 8 * MB);   // 8 MB (reused as rl buffer)
  uint16_t* Wb  = (uint16_t*)(ws + 16 * MB);  // 6 MB
  uint16_t* Wob = (uint16_t*)(ws + 22 * MB);  // 2 MB
  uint16_t* Qb  = (uint16_t*)(ws + 24 * MB);  // 8 MB (b,h,t,d)
  uint16_t* Kb  = (uint16_t*)(ws + 32 * MB);  // 8 MB (b,h,s,d)
  uint16_t* Vt  = (uint16_t*)(ws + 40 * MB);  // 8 MB (b,h,d,s)
  uint16_t* AO  = Xq;                         // alias: Xq dead after gemm_qkv
  float*    rlws = (float*)(ws + 8 * MB);     // alias: Xk dead after gemm_qkv

  float* out = (float*)d_out;
  float* avg = out + 4194304;
  // bits (512 KB) parked in the out region: only read by attn, which
  // completes before tail's gemm_out path overwrites it.
  uint32_t* bits = (uint32_t*)out;

  // fused cast (12288 blocks) + bitpack (16384 blocks)
  prep<<<28672, 256, 0, stream>>>(query, key, ipw, opw, hard,
                                  Xq, Xk, Wb, Wob, bits);

  // fused Q-proj (256) + KV-proj (512), 128^2 2-phase + XCD swizzle
  gemm_qkv<<<768, 256, 0, stream>>>(Xq, Xk, Wb, ipb, Qb, Kb, Vt);

  // attention (swapped-operand, swizzled LDS): AO + 1/rowsum (rl -> ws)
  attn_kernel<<<512, 256, 0, stream>>>(Qb, Kb, Vt, bits, AO, rlws);

  // fused head-averaged attention map + out-projection
  tail<<<1024, 256, 0, stream>>>(Qb, Kb, rlws, hard, AO, Wob, opb, out, avg);
}

// Round 6
// 227.001 us; speedup vs baseline: 1.1769x; 1.0118x over previous
//
#include <hip/hip_runtime.h>
#include <cstdint>
#include <cstddef>

// ---------- common ----------
typedef __bf16 bf16x8 __attribute__((ext_vector_type(8)));
typedef float  f32x4  __attribute__((ext_vector_type(4)));
typedef unsigned short u16x8 __attribute__((ext_vector_type(8)));

__device__ __forceinline__ uint16_t f2bf(float f) {
  uint32_t u = __float_as_uint(f);
  u += 0x7fffu + ((u >> 16) & 1u);          // round-to-nearest-even
  return (uint16_t)(u >> 16);
}
__device__ __forceinline__ float bf2f(uint16_t u) {
  return __uint_as_float((uint32_t)u << 16);
}
// packed f32x2 -> bf16x2 (dst.lo=lo, dst.hi=hi), RTNE in HW
__device__ __forceinline__ uint32_t cvtpk(float lo, float hi) {
  uint32_t r;
  asm("v_cvt_pk_bf16_f32 %0, %1, %2" : "=v"(r) : "v"(lo), "v"(hi));
  return r;
}

__device__ __forceinline__ f32x4 mfma16(bf16x8 a, bf16x8 b, f32x4 c) {
  return __builtin_amdgcn_mfma_f32_16x16x32_bf16(a, b, c, 0, 0, 0);
}

#define GLD_TO_LDS16(gptr, lptr)                                                   \
  __builtin_amdgcn_global_load_lds(                                                \
      (const __attribute__((address_space(1))) void*)(gptr),                       \
      (__attribute__((address_space(3))) void*)(lptr), 16, 0, 0)

// ---------- prep: fused fp32->bf16 cast of 4 tensors + hard bitpack ----------
__global__ void prep(const float* __restrict__ q, const float* __restrict__ k,
                     const float* __restrict__ w, const float* __restrict__ wo,
                     const float* __restrict__ hard,
                     uint16_t* __restrict__ Xq, uint16_t* __restrict__ Xk,
                     uint16_t* __restrict__ Wb, uint16_t* __restrict__ Wob,
                     uint32_t* __restrict__ bits) {
  const int bid = blockIdx.x;
  if (bid < 12288) {
    int i = bid * 256 + threadIdx.x;
    const float* src;
    uint16_t* dst;
    int off;
    if (i < 1048576)      { src = q;  dst = Xq;  off = i; }
    else if (i < 2097152) { src = k;  dst = Xk;  off = i - 1048576; }
    else if (i < 2883584) { src = w;  dst = Wb;  off = i - 2097152; }
    else                  { src = wo; dst = Wob; off = i - 2883584; }
    float4 v = ((const float4*)src)[off];
    ushort4 o;
    o.x = f2bf(v.x); o.y = f2bf(v.y); o.z = f2bf(v.z); o.w = f2bf(v.w);
    ((ushort4*)dst)[off] = o;
  } else {
    int base = (bid - 12288) * 1024;
#pragma unroll
    for (int c = 0; c < 4; c++) {
      int i = base + c * 256 + threadIdx.x;
      unsigned long long m = __ballot(hard[i] != 0.0f);
      if ((threadIdx.x & 63) == 0) {
        int wd = i >> 5;
        bits[wd]     = (uint32_t)m;
        bits[wd + 1] = (uint32_t)(m >> 32);
      }
    }
  }
}

// ---------- fused Q + KV projection, 128x128 tiles, BK=64, grid 768 ----------
// R12: kept the 2-phase structure (R1-class, best measured) but BK 32->64:
//  - halves the per-K-step vmcnt(0)+barrier drains (32 -> 16),
//  - 128B LDS rows with both-sides XOR swizzle (read: byte ^ (l16&7)<<4;
//    write: gld_lds linear dst + pre-swizzled global col ((lane&7)^(lane>>3))<<4
//    -- the involution verified conflict-free + numerically in R2's 8-phase).
//    Kills the 3.1M bank-conflict cycles of the 64B-row layout (16-way within
//    a quarter-wave -> 2-way free).
// XCD-bijective block swizzle kept (FETCH 68.7 -> 23.7 MB measured).
__global__ __launch_bounds__(256)
void gemm_qkv(const uint16_t* __restrict__ Xq, const uint16_t* __restrict__ Xk,
              const uint16_t* __restrict__ Wb, const float* __restrict__ ipb,
              uint16_t* __restrict__ Qb, uint16_t* __restrict__ Kb,
              uint16_t* __restrict__ Vt) {
  __shared__ __align__(16) char As[128 * 128];   // 16 KB: 128 rows x 128B (swz)
  __shared__ __align__(16) char Bs[128 * 128];   // 16 KB
  const int tid  = threadIdx.x;
  const int wave = tid >> 6, lane = tid & 63;
  const int quad = lane >> 4, l16 = lane & 15;
  const int sw = (l16 & 7) << 4;                 // read-side XOR swizzle

  const int swz = (blockIdx.x & 7) * 96 + (blockIdx.x >> 3);  // XCD-bijective
  const uint16_t *A, *B;
  const float* bias;
  int bm, bn, mode;
  if (swz < 256) {
    mode = 0; A = Xq; B = Wb; bias = ipb;
    bm = swz >> 3; bn = swz & 7;
  } else {
    mode = 1; A = Xk; B = Wb + (1 << 20); bias = ipb + 1024;
    int t = swz - 256; bm = t >> 4; bn = t & 15;
  }
  const int wm = (wave >> 1) << 6, wn = (wave & 1) << 6;

  // staging: 8 lanes per 128B row; pre-swizzled source column
  const int lrow = lane >> 3;
  const int scol = ((lane & 7) ^ lrow) << 4;
  const char* Ag = (const char*)A + (size_t)(bm * 128) * 2048;
  const char* Bg = (const char*)B + (size_t)(bn * 128) * 2048;

  f32x4 acc[4][4] = {};

  for (int k0 = 0; k0 < 2048; k0 += 128) {   // k0 in BYTES (BK=64 elems)
    __syncthreads();
#pragma unroll
    for (int j = 0; j < 4; j++) {
      const int rbase = j * 32 + wave * 8;
      GLD_TO_LDS16(Ag + (size_t)(rbase + lrow) * 2048 + k0 + scol,
                   As + rbase * 128);
      GLD_TO_LDS16(Bg + (size_t)(rbase + lrow) * 2048 + k0 + scol,
                   Bs + rbase * 128);
    }
    __syncthreads();

    bf16x8 af[4][2], bfr[4][2];
#pragma unroll
    for (int i = 0; i < 4; i++) {
      const char* pa = As + (wm + i * 16 + l16) * 128;
      const char* pb = Bs + (wn + i * 16 + l16) * 128;
#pragma unroll
      for (int ks = 0; ks < 2; ks++) {
        af[i][ks]  = *(const bf16x8*)(pa + ((ks * 64 + quad * 16) ^ sw));
        bfr[i][ks] = *(const bf16x8*)(pb + ((ks * 64 + quad * 16) ^ sw));
      }
    }
#pragma unroll
    for (int ks = 0; ks < 2; ks++)
#pragma unroll
      for (int mi = 0; mi < 4; mi++)
#pragma unroll
        for (int ni = 0; ni < 4; ni++)
          acc[mi][ni] = mfma16(af[mi][ks], bfr[ni][ks], acc[mi][ni]);
  }

#pragma unroll
  for (int mi = 0; mi < 4; mi++)
#pragma unroll
    for (int ni = 0; ni < 4; ni++)
#pragma unroll
      for (int r = 0; r < 4; r++) {
        int gi = bm * 128 + wm + mi * 16 + quad * 4 + r;  // row = t*4+b
        int gf = bn * 128 + wn + ni * 16 + l16;
        float c = acc[mi][ni][r] + bias[gf];
        if (mode == 0) {
          c *= 0.125f;  // HD^-0.5
          int t = gi >> 2, b = gi & 3, h = gf >> 6, d = gf & 63;
          Qb[((((size_t)b * 16 + h) * 1024 + t) << 6) + d] = f2bf(c);
        } else {
          int s = gi >> 2, b = gi & 3;
          if (gf < 1024) {
            int h = gf >> 6, d = gf & 63;
            Kb[((((size_t)b * 16 + h) * 1024 + s) << 6) + d] = f2bf(c);
          } else {
            int fv = gf - 1024, h = fv >> 6, d = fv & 63;
            Vt[((((size_t)b * 16 + h) * 64 + d) << 10) + s] = f2bf(c);
          }
        }
      }
}

// ---------- attention: swapped-operand QK/PV, XOR-swizzled LDS ----------
__global__ __launch_bounds__(256, 2)
void attn_kernel(const uint16_t* __restrict__ qb, const uint16_t* __restrict__ kb,
                 const uint16_t* __restrict__ vtb, const uint32_t* __restrict__ bits,
                 uint16_t* __restrict__ attn_out, float* __restrict__ rlout) {
  __shared__ __align__(16) uint16_t Ks[128 * 64];    // [s][d] swizzled, 16 KB
  __shared__ __align__(16) uint16_t Vs[64 * 128];    // [d][s] swizzled, 16 KB
  __shared__ __align__(16) uint16_t Pb[4 * 32 * 128];// per-wave [t32][s128], 32 KB

  const int bid = blockIdx.x;              // 512 blocks
  const int xcd = bid & 7, j = bid >> 3;   // round-robin dispatch -> XCD
  const int slab = xcd * 8 + (j >> 3);     // 8 (b,h) slabs per XCD
  const int b = slab >> 4, h = slab & 15;
  const int t0 = (j & 7) << 7;             // 128 t-rows per block
  const int tid = threadIdx.x, wave = tid >> 6, lane = tid & 63;
  const int quad = lane >> 4, l16 = lane & 15;
  const int sw = (l16 & 7) << 4;           // XOR swizzle for row=l16 reads
  const size_t bh = (size_t)b * 16 + h;
  const int tw = t0 + wave * 32;
  const int ta = tw + l16, tb = ta + 16;   // lane's two t rows
  char* PwA = (char*)(Pb + wave * (32 * 128)) + l16 * 256;
  char* PwB = PwA + 16 * 256;

  // Q B-frags (op1: col=t=l16), rows ta / tb
  const uint16_t* qA = qb + ((bh << 10) + ta) * 64;
  bf16x8 aqA0 = *(const bf16x8*)(qA + quad * 8);
  bf16x8 aqA1 = *(const bf16x8*)(qA + 32 + quad * 8);
  bf16x8 aqB0 = *(const bf16x8*)(qA + 1024 + quad * 8);
  bf16x8 aqB1 = *(const bf16x8*)(qA + 1024 + 32 + quad * 8);

  f32x4 accA[4] = {}, accB[4] = {};
  float smA = 0.f, smB = 0.f;

  const int kr = tid >> 3, kc8 = tid & 7;    // K staging: 32 rows/round
  const int vr = tid >> 4, vc16 = tid & 15;  // V staging: 16 rows/round

  const uint32_t* bA = bits + (((size_t)(b << 10) + ta) << 5);
  const uint32_t* bB = bits + (((size_t)(b << 10) + tb) << 5);

  // prologue: coalesced loads of chunk 0 + its mask words
  u16x8 kreg[4], vreg[4];
#pragma unroll
  for (int r = 0; r < 4; r++)
    kreg[r] = *(const u16x8*)(kb + (bh << 16) + (size_t)(r * 256 + tid) * 8);
#pragma unroll
  for (int r = 0; r < 4; r++)
    vreg[r] = *(const u16x8*)(vtb + (((bh << 6) + r * 16 + vr) << 10) + vc16 * 8);
  uint4 uA = *(const uint4*)bA;
  uint4 uB = *(const uint4*)bB;

  for (int sc = 0; sc < 8; sc++) {
    // pre-shifted mask words for this chunk (from prefetched uA/uB)
    uint32_t wA[4] = {uA.x >> (quad * 4), uA.y >> (quad * 4),
                      uA.z >> (quad * 4), uA.w >> (quad * 4)};
    uint32_t wB[4] = {uB.x >> (quad * 4), uB.y >> (quad * 4),
                      uB.z >> (quad * 4), uB.w >> (quad * 4)};

    __syncthreads();  // prior chunk's LDS reads done; staging loads drained
#pragma unroll
    for (int r = 0; r < 4; r++) {
      const int row = r * 32 + kr;
      *(u16x8*)((char*)Ks + row * 128 + ((kc8 * 16) ^ ((row & 7) << 4))) = kreg[r];
    }
#pragma unroll
    for (int r = 0; r < 4; r++) {
      const int row = r * 16 + vr;
      *(u16x8*)((char*)Vs + row * 256 + ((vc16 * 16) ^ ((row & 7) << 4))) = vreg[r];
    }
    __syncthreads();  // staging visible

    if (sc < 7) {  // T14: issue next chunk's loads; latency hides under compute
      const uint16_t* kbase = kb + (bh << 16) + (size_t)(sc + 1) * 8192;
#pragma unroll
      for (int r = 0; r < 4; r++)
        kreg[r] = *(const u16x8*)(kbase + (size_t)(r * 256 + tid) * 8);
#pragma unroll
      for (int r = 0; r < 4; r++)
        vreg[r] = *(const u16x8*)(vtb + (((bh << 6) + r * 16 + vr) << 10) +
                                  (sc + 1) * 128 + vc16 * 8);
      uA = *(const uint4*)(bA + (sc + 1) * 4);
      uB = *(const uint4*)(bB + (sc + 1) * 4);
    }

    // QK^T (swapped: D[s=quad*4+r][t=l16]) + streamed exp -> packed P rows
#pragma unroll
    for (int nn = 0; nn < 8; nn++) {
      const char* kbp = (const char*)Ks + (nn * 16 + l16) * 128;
      bf16x8 bk0 = *(const bf16x8*)(kbp + ((quad * 16) ^ sw));
      bf16x8 bk1 = *(const bf16x8*)(kbp + ((64 + quad * 16) ^ sw));
      f32x4 cA = {}, cB = {};
      cA = mfma16(bk0, aqA0, cA); cA = mfma16(bk1, aqA1, cA);
      cB = mfma16(bk0, aqB0, cB); cB = mfma16(bk1, aqB1, cB);
      const uint32_t mA = wA[nn >> 1] >> ((nn & 1) * 16);
      const uint32_t mB = wB[nn >> 1] >> ((nn & 1) * 16);
      float eA[4], eB[4];
#pragma unroll
      for (int r = 0; r < 4; r++) {
        eA[r] = __expf(cA[r]); smA += eA[r];
        eB[r] = __expf(cB[r]); smB += eB[r];
        eA[r] = ((mA >> r) & 1) ? eA[r] : 0.f;  // mask AFTER rowsum (softmax*hard)
        eB[r] = ((mB >> r) & 1) ? eB[r] : 0.f;
      }
      const int pc = (nn * 32 + quad * 8) ^ sw;
      *(uint2*)(PwA + pc) = make_uint2(cvtpk(eA[0], eA[1]), cvtpk(eA[2], eA[3]));
      *(uint2*)(PwB + pc) = make_uint2(cvtpk(eB[0], eB[1]), cvtpk(eB[2], eB[3]));
    }

    // PV (swapped: D[d=quad*4+r][t=l16]); P wave-private -> no barrier
#pragma unroll
    for (int kc = 0; kc < 4; kc++) {
      const int pcb = (kc * 64 + quad * 16) ^ sw;
      bf16x8 apA = *(const bf16x8*)(PwA + pcb);
      bf16x8 apB = *(const bf16x8*)(PwB + pcb);
#pragma unroll
      for (int dt = 0; dt < 4; dt++) {
        bf16x8 bv = *(const bf16x8*)((const char*)Vs + (dt * 16 + l16) * 256 +
                                     ((kc * 64 + quad * 16) ^ sw));
        accA[dt] = mfma16(bv, apA, accA[dt]);
        accB[dt] = mfma16(bv, apB, accB[dt]);
      }
    }
  }

  // row-sums: t is lane-local; reduce across quads only
  smA += __shfl_xor(smA, 16); smA += __shfl_xor(smA, 32);
  smB += __shfl_xor(smB, 16); smB += __shfl_xor(smB, 32);
  const float rlA = 1.0f / smA, rlB = 1.0f / smB;
  if (quad == 0) rlout[(bh << 10) + ta] = rlA;
  if (quad == 1) rlout[(bh << 10) + tb] = rlB;

  // O epilogue: 4 consecutive d per lane -> packed 8B stores
#pragma unroll
  for (int dt = 0; dt < 4; dt++) {
    uint2 oA = make_uint2(cvtpk(accA[dt][0] * rlA, accA[dt][1] * rlA),
                          cvtpk(accA[dt][2] * rlA, accA[dt][3] * rlA));
    *(uint2*)(attn_out + ((size_t)(ta * 4 + b) << 10) + h * 64 + dt * 16 + quad * 4) = oA;
    uint2 oB = make_uint2(cvtpk(accB[dt][0] * rlB, accB[dt][1] * rlB),
                          cvtpk(accB[dt][2] * rlB, accB[dt][3] * rlB));
    *(uint2*)(attn_out + ((size_t)(tb * 4 + b) << 10) + h * 64 + dt * 16 + quad * 4) = oB;
  }
}

// ---------- tail: fused avg (blocks 0..511) + out-projection (512..1023) ----
__global__ __launch_bounds__(256, 4)
void tail(const uint16_t* __restrict__ qb, const uint16_t* __restrict__ kb,
          const float* __restrict__ rlin, const float* __restrict__ hard,
          const uint16_t* __restrict__ Ao, const uint16_t* __restrict__ Bw,
          const float* __restrict__ opb,
          float* __restrict__ out, float* __restrict__ avgout) {
  __shared__ __align__(16) char smem[16384];
  const int bid = blockIdx.x;
  const int tid = threadIdx.x, wave = tid >> 6, lane = tid & 63;
  const int quad = lane >> 4, l16 = lane & 15;

  if (bid < 512) {
    // ---- avg path: swapped-operand QK, swizzled K, float4 stores ----
    uint16_t* Ks = (uint16_t*)smem;          // 16 KB swizzled K-tile
    const int xcd = bid & 7, j = bid >> 3;
    const int b  = xcd >> 1;
    const int t0 = ((xcd & 1) * 8 + (j >> 3)) << 6;
    const int s0 = (j & 7) << 7;
    const int sw = (l16 & 7) << 4;
    const int tr = t0 + wave * 16 + l16;     // lane's t row
    const int kr = tid >> 3, kc8 = tid & 7;

    float av[8][4] = {};

    u16x8 kreg[4];
    {
      const uint16_t* kb0 = kb + ((((size_t)b * 16) << 10) + s0) * 64;
#pragma unroll
      for (int r = 0; r < 4; r++)
        kreg[r] = *(const u16x8*)(kb0 + (size_t)(r * 256 + tid) * 8);
    }

    for (int hh = 0; hh < 16; hh++) {
      __syncthreads();
#pragma unroll
      for (int r = 0; r < 4; r++) {
        const int row = r * 32 + kr;
        *(u16x8*)((char*)Ks + row * 128 + ((kc8 * 16) ^ ((row & 7) << 4))) = kreg[r];
      }
      __syncthreads();
      if (hh < 15) {  // prefetch next head's K-tile under compute
        const uint16_t* kb2 = kb + ((((size_t)b * 16 + hh + 1) << 10) + s0) * 64;
#pragma unroll
        for (int r = 0; r < 4; r++)
          kreg[r] = *(const u16x8*)(kb2 + (size_t)(r * 256 + tid) * 8);
      }

      const size_t bh = (size_t)b * 16 + hh;
      const uint16_t* qrow = qb + ((bh << 10) + tr) * 64;
      bf16x8 aq0 = *(const bf16x8*)(qrow + quad * 8);
      bf16x8 aq1 = *(const bf16x8*)(qrow + 32 + quad * 8);
      const float rl = rlin[(bh << 10) + tr];

#pragma unroll
      for (int n = 0; n < 8; n++) {
        const char* kbp = (const char*)Ks + (n * 16 + l16) * 128;
        bf16x8 bk0 = *(const bf16x8*)(kbp + ((quad * 16) ^ sw));
        bf16x8 bk1 = *(const bf16x8*)(kbp + ((64 + quad * 16) ^ sw));
        f32x4 c = {};
        c = mfma16(bk0, aq0, c);
        c = mfma16(bk1, aq1, c);
#pragma unroll
        for (int r = 0; r < 4; r++) av[n][r] += __expf(c[r]) * rl;
      }
    }

    // mask directly from immutable hard input (fp32 {0,1}), float4 per n
    const float* hrow = hard + (((size_t)(b << 10) + tr) << 10) + s0 + quad * 4;
    float* orow = avgout + ((size_t)(b << 10) + tr) * 1024 + s0 + quad * 4;
#pragma unroll
    for (int n = 0; n < 8; n++) {
      float4 hm = *(const float4*)(hrow + n * 16);
      float4 f;
      f.x = av[n][0] * (hm.x != 0.f ? 0.0625f : 0.f);
      f.y = av[n][1] * (hm.y != 0.f ? 0.0625f : 0.f);
      f.z = av[n][2] * (hm.z != 0.f ? 0.0625f : 0.f);
      f.w = av[n][3] * (hm.w != 0.f ? 0.0625f : 0.f);
      *(float4*)(orow + n * 16) = f;
    }
  } else {
    // ---- out-projection path: 64x128 tiles, XCD swizzle (512 = 8*64) ----
    uint16_t* As = (uint16_t*)smem;            // 4 KB
    uint16_t* Bs = (uint16_t*)(smem + 4096);   // 8 KB
    const int u = bid - 512;
    const int swz = (u & 7) * 64 + (u >> 3);   // same-bm blocks on one XCD
    const int bm = swz >> 3, bn = swz & 7;
    const int wm = (wave >> 1) << 5, wn = (wave & 1) << 6;
    const int K = 1024;

    f32x4 acc[2][4] = {};

    for (int k0 = 0; k0 < K; k0 += 32) {
      __syncthreads();
      {
        int c   = wave * 64 + lane;
        int row = c >> 2, kc = c & 3;
        const uint16_t* ga = Ao + (size_t)(bm * 64 + row) * K + k0 + kc * 8;
        GLD_TO_LDS16(ga, As + (size_t)(wave * 64) * 8);
      }
#pragma unroll
      for (int jj = 0; jj < 2; jj++) {
        int c   = wave * 128 + jj * 64 + lane;
        int row = c >> 2, kc = c & 3;
        const uint16_t* gb = Bw + (size_t)(bn * 128 + row) * K + k0 + kc * 8;
        GLD_TO_LDS16(gb, Bs + (size_t)(wave * 128 + jj * 64) * 8);
      }
      __syncthreads();

      bf16x8 af[2], bfr[4];
#pragma unroll
      for (int i = 0; i < 2; i++)
        af[i] = *(const bf16x8*)(As + (wm + i * 16 + l16) * 32 + quad * 8);
#pragma unroll
      for (int i = 0; i < 4; i++)
        bfr[i] = *(const bf16x8*)(Bs + (wn + i * 16 + l16) * 32 + quad * 8);
#pragma unroll
      for (int mi = 0; mi < 2; mi++)
#pragma unroll
        for (int ni = 0; ni < 4; ni++)
          acc[mi][ni] = mfma16(af[mi], bfr[ni], acc[mi][ni]);
    }

#pragma unroll
    for (int mi = 0; mi < 2; mi++)
#pragma unroll
      for (int ni = 0; ni < 4; ni++)
#pragma unroll
        for (int r = 0; r < 4; r++) {
          int gi = bm * 64 + wm + mi * 16 + quad * 4 + r;
          int gf = bn * 128 + wn + ni * 16 + l16;
          out[(size_t)gi * 1024 + gf] = acc[mi][ni][r] + opb[gf];
        }
  }
}

// ---------- launch ----------
extern "C" void kernel_launch(void* const* d_in, const int* in_sizes, int n_in,
                              void* d_out, int out_size, void* d_ws, size_t ws_size,
                              hipStream_t stream) {
  const float* query = (const float*)d_in[0];
  const float* key   = (const float*)d_in[1];
  const float* hard  = (const float*)d_in[2];
  const float* ipw   = (const float*)d_in[3];
  const float* ipb   = (const float*)d_in[4];
  const float* opw   = (const float*)d_in[5];
  const float* opb   = (const float*)d_in[6];

  char* ws = (char*)d_ws;
  const size_t MB = 1ull << 20;
  uint16_t* Xq  = (uint16_t*)(ws + 0);        // 8 MB (reused as attn_out)
  uint16_t* Xk  = (uint16_t*)(ws + 8 * MB);   // 8 MB (reused as rl buffer)
  uint16_t* Wb  = (uint16_t*)(ws + 16 * MB);  // 6 MB
  uint16_t* Wob = (uint16_t*)(ws + 22 * MB);  // 2 MB
  uint16_t* Qb  = (uint16_t*)(ws + 24 * MB);  // 8 MB (b,h,t,d)
  uint16_t* Kb  = (uint16_t*)(ws + 32 * MB);  // 8 MB (b,h,s,d)
  uint16_t* Vt  = (uint16_t*)(ws + 40 * MB);  // 8 MB (b,h,d,s)
  uint16_t* AO  = Xq;                         // alias: Xq dead after gemm_qkv
  float*    rlws = (float*)(ws + 8 * MB);     // alias: Xk dead after gemm_qkv

  float* out = (float*)d_out;
  float* avg = out + 4194304;
  // bits (512 KB) parked in the out region: only read by attn, which
  // completes before tail's gemm_out path overwrites it.
  uint32_t* bits = (uint32_t*)out;

  // fused cast (12288 blocks) + bitpack (4096 blocks, 4x vectorized)
  prep<<<16384, 256, 0, stream>>>(query, key, ipw, opw, hard,
                                  Xq, Xk, Wb, Wob, bits);

  // fused Q-proj (256) + KV-proj (512), 128^2 BK=64 2-phase + swizzles
  gemm_qkv<<<768, 256, 0, stream>>>(Xq, Xk, Wb, ipb, Qb, Kb, Vt);

  // attention (swapped-operand, swizzled LDS): AO + 1/rowsum (rl -> ws)
  attn_kernel<<<512, 256, 0, stream>>>(Qb, Kb, Vt, bits, AO, rlws);

  // fused head-averaged attention map + out-projection
  tail<<<1024, 256, 0, stream>>>(Qb, Kb, rlws, hard, AO, Wob, opb, out, avg);
}